// Round 1
// baseline (123.429 us; speedup 1.0000x reference)
//
#include <hip/hip_runtime.h>
#include <hip/hip_bf16.h>
#include <cstdint>
#include <cstddef>

#define NUM_CLASS 1000
#define NPAD      1024
#define LOW_DIM   128
#define B_UPD     1024
#define B_SIM     65536

typedef short bf16x8 __attribute__((ext_vector_type(8)));
typedef float f32x4  __attribute__((ext_vector_type(4)));

__device__ __forceinline__ unsigned short f2bf(float f) {
  union { float f; unsigned u; } a; a.f = f;
  unsigned u = a.u;
  return (unsigned short)((u + 0x7fffu + ((u >> 16) & 1u)) >> 16);  // RNE
}

// ---------- kernel 1: per-class sequential EMA + L2 normalize -> bf16 ----------
// Reference scans samples in order; updates to different labels commute, so a
// per-class in-order scan reproduces the lax.scan exactly. Grid = NPAD blocks
// (classes >= NUM_CLASS write zero rows, used as N-padding for the GEMM).
__global__ void proto_update_kernel(const float* __restrict__ pred_feat,
                                    const int*   __restrict__ labels,
                                    const float* __restrict__ protos_in,
                                    unsigned short* __restrict__ protos_bf) {
  int c = blockIdx.x;    // 0..1023
  int d = threadIdx.x;   // 0..127
  __shared__ int slab[B_UPD];
  for (int i = d; i < B_UPD; i += 128) slab[i] = labels[i];
  __syncthreads();

  float p = 0.0f;
  if (c < NUM_CLASS) {
    p = protos_in[c * LOW_DIM + d];
    const float M  = 0.99f;
    const float OM = 1.0f - 0.99f;
    for (int i = 0; i < B_UPD; ++i) {
      if (slab[i] == c) {               // block-uniform branch, cheap skip
        p = M * p + OM * pred_feat[(size_t)i * LOW_DIM + d];
      }
    }
  }
  // row norm over 128 threads (2 waves)
  float sq = p * p;
  #pragma unroll
  for (int o = 1; o < 64; o <<= 1) sq += __shfl_xor(sq, o, 64);
  __shared__ float wsum[2];
  if ((d & 63) == 0) wsum[d >> 6] = sq;
  __syncthreads();
  float total = wsum[0] + wsum[1];
  float out = p / fmaxf(sqrtf(total), 1e-12f);   // c>=1000: 0/1e-12 = 0
  protos_bf[c * LOW_DIM + d] = f2bf(out);
}

// ---------- kernel 2: feat f32 -> bf16 (one-shot, 48 MB traffic) ----------
__global__ void cvt_feat_kernel(const float* __restrict__ src,
                                unsigned short* __restrict__ dst) {
  size_t idx = (size_t)blockIdx.x * blockDim.x + threadIdx.x;  // 8-elem chunk
  const float4* s = reinterpret_cast<const float4*>(src) + idx * 2;
  float4 v0 = s[0], v1 = s[1];
  uint4 q;
  q.x = f2bf(v0.x) | ((unsigned)f2bf(v0.y) << 16);
  q.y = f2bf(v0.z) | ((unsigned)f2bf(v0.w) << 16);
  q.z = f2bf(v1.x) | ((unsigned)f2bf(v1.y) << 16);
  q.w = f2bf(v1.z) | ((unsigned)f2bf(v1.w) << 16);
  reinterpret_cast<uint4*>(dst)[idx] = q;
}

// ---------- kernel 3: C[65536,1000] = A[65536,128] @ B[1024,128]^T ----------
// BM=BN=128, K=128 staged once (no K-tile loop). 4 waves, each owns 64x64.
// LDS rows are 256B; XOR swizzle byte^=((row&7)<<4) applied on BOTH ds_write
// and ds_read (same involution) to spread the stride-256B fragment reads
// across all banks.
#define BM  128
#define BN  128
#define TPB 256

template<bool ABF16>
__global__ __launch_bounds__(TPB, 2)
void gemm_sim_kernel(const void* __restrict__ Av,
                     const unsigned short* __restrict__ Bp,
                     float* __restrict__ C) {
  __shared__ unsigned char Als[BM * 256];   // 32 KB
  __shared__ unsigned char Bls[BN * 256];   // 32 KB
  int bid  = blockIdx.x;                 // 4096 = 512 m-tiles x 8 n-tiles
  int xcd  = bid & 7, pos = bid >> 3;
  int orig = xcd * 512 + pos;            // bijective XCD swizzle (4096%8==0)
  int mblk = orig >> 3;                  // n-major: 8 consecutive orig ids
  int nblk = orig & 7;                   //   share one A tile within an XCD
  int m0 = mblk * BM;
  int n0 = nblk * BN;
  int t  = threadIdx.x;

  // ---- stage A: 128 rows x 128 bf16 ----
  if (ABF16) {
    const unsigned short* A = (const unsigned short*)Av;
    #pragma unroll
    for (int it = 0; it < 8; ++it) {
      int idx = it * TPB + t;
      int row = idx >> 4, c8 = idx & 15;
      uint4 v = *reinterpret_cast<const uint4*>(A + (size_t)(m0 + row) * LOW_DIM + c8 * 8);
      *reinterpret_cast<uint4*>(Als + row * 256 + ((c8 * 16) ^ ((row & 7) << 4))) = v;
    }
  } else {
    const float* A = (const float*)Av;
    #pragma unroll
    for (int it = 0; it < 8; ++it) {
      int idx = it * TPB + t;
      int row = idx >> 4, c8 = idx & 15;
      const float4* s = reinterpret_cast<const float4*>(A + (size_t)(m0 + row) * LOW_DIM + c8 * 8);
      float4 v0 = s[0], v1 = s[1];
      uint4 q;
      q.x = f2bf(v0.x) | ((unsigned)f2bf(v0.y) << 16);
      q.y = f2bf(v0.z) | ((unsigned)f2bf(v0.w) << 16);
      q.z = f2bf(v1.x) | ((unsigned)f2bf(v1.y) << 16);
      q.w = f2bf(v1.z) | ((unsigned)f2bf(v1.w) << 16);
      *reinterpret_cast<uint4*>(Als + row * 256 + ((c8 * 16) ^ ((row & 7) << 4))) = q;
    }
  }
  // ---- stage B: 128 rows x 128 bf16 (protos, zero-padded past 1000) ----
  #pragma unroll
  for (int it = 0; it < 8; ++it) {
    int idx = it * TPB + t;
    int row = idx >> 4, c8 = idx & 15;
    uint4 v = *reinterpret_cast<const uint4*>(Bp + (size_t)(n0 + row) * LOW_DIM + c8 * 8);
    *reinterpret_cast<uint4*>(Bls + row * 256 + ((c8 * 16) ^ ((row & 7) << 4))) = v;
  }
  __syncthreads();

  int lane = t & 63;
  int w    = t >> 6;
  int wr   = (w >> 1) * 64;   // wave row offset
  int wc   = (w & 1) * 64;    // wave col offset
  int lr   = lane & 15;       // fragment row/col within 16
  int lkb  = (lane >> 4) * 16;// byte offset of this lane's 8-elem k-chunk

  f32x4 acc[4][4];
  #pragma unroll
  for (int m = 0; m < 4; ++m)
    #pragma unroll
    for (int n = 0; n < 4; ++n)
      acc[m][n] = (f32x4){0.f, 0.f, 0.f, 0.f};

  #pragma unroll
  for (int kk = 0; kk < 4; ++kk) {       // K = 4 x 32
    int kb = kk * 64 + lkb;
    bf16x8 af[4], bg[4];
    #pragma unroll
    for (int m = 0; m < 4; ++m) {
      int row = wr + m * 16 + lr;
      af[m] = *reinterpret_cast<const bf16x8*>(Als + row * 256 + (kb ^ ((row & 7) << 4)));
    }
    #pragma unroll
    for (int n = 0; n < 4; ++n) {
      int row = wc + n * 16 + lr;
      bg[n] = *reinterpret_cast<const bf16x8*>(Bls + row * 256 + (kb ^ ((row & 7) << 4)));
    }
    #pragma unroll
    for (int m = 0; m < 4; ++m)
      #pragma unroll
      for (int n = 0; n < 4; ++n)
        acc[m][n] = __builtin_amdgcn_mfma_f32_16x16x32_bf16(af[m], bg[n], acc[m][n], 0, 0, 0);
  }

  // ---- epilogue: C/D layout col=lane&15, row=(lane>>4)*4+reg ----
  #pragma unroll
  for (int m = 0; m < 4; ++m) {
    int rbase = m0 + wr + m * 16 + (lane >> 4) * 4;
    #pragma unroll
    for (int n = 0; n < 4; ++n) {
      int col = n0 + wc + n * 16 + lr;
      if (col < NUM_CLASS) {
        #pragma unroll
        for (int r = 0; r < 4; ++r)
          C[(size_t)(rbase + r) * NUM_CLASS + col] = acc[m][n][r];
      }
    }
  }
}

extern "C" void kernel_launch(void* const* d_in, const int* in_sizes, int n_in,
                              void* d_out, int out_size, void* d_ws, size_t ws_size,
                              hipStream_t stream) {
  const float* pred_feat = (const float*)d_in[0];   // [1024,128]
  const int*   labels    = (const int*)d_in[1];     // [1024]
  const float* protos    = (const float*)d_in[2];   // [1000,128]
  const float* feat      = (const float*)d_in[3];   // [65536,128]
  float* out = (float*)d_out;                       // [65536,1000]

  unsigned char* ws = (unsigned char*)d_ws;
  unsigned short* protos_bf = (unsigned short*)ws;          // 1024x128 bf16
  const size_t protoBytes = (size_t)NPAD * LOW_DIM * 2;     // 256 KB

  proto_update_kernel<<<NPAD, 128, 0, stream>>>(pred_feat, labels, protos, protos_bf);

  const size_t featBytes = (size_t)B_SIM * LOW_DIM * 2;     // 16 MB
  if (ws_size >= protoBytes + featBytes) {
    unsigned short* feat_bf = (unsigned short*)(ws + protoBytes);
    cvt_feat_kernel<<<(B_SIM * LOW_DIM / 8) / 256, 256, 0, stream>>>(feat, feat_bf);
    gemm_sim_kernel<true><<<(B_SIM / BM) * (NPAD / BN), TPB, 0, stream>>>(feat_bf, protos_bf, out);
  } else {
    // fallback: convert A tiles in-register during staging (f32 reads are
    // L3-resident; only needs 256 KB of workspace)
    gemm_sim_kernel<false><<<(B_SIM / BM) * (NPAD / BN), TPB, 0, stream>>>(feat, protos_bf, out);
  }
}